// Round 3
// baseline (665.490 us; speedup 1.0000x reference)
//
#include <hip/hip_runtime.h>

typedef unsigned short u16;
typedef unsigned int   u32;
typedef __bf16 bf16x8 __attribute__((ext_vector_type(8)));
typedef float  f32x4  __attribute__((ext_vector_type(4)));

// ---------- helpers ----------
__device__ __forceinline__ float bf2f(u16 v){ u32 u = ((u32)v) << 16; float f; __builtin_memcpy(&f,&u,4); return f; }
__device__ __forceinline__ u16 f2bf(float f){ u32 u; __builtin_memcpy(&u,&f,4); u32 r = (u + 0x7FFFu + ((u>>16)&1u)) >> 16; return (u16)r; }
__device__ __forceinline__ float silu(float v){ return v / (1.f + __expf(-v)); }

__device__ __forceinline__ void gload_lds16(const u16* g, u16* l){
  __builtin_amdgcn_global_load_lds((const __attribute__((address_space(1))) void*)g,
                                   (__attribute__((address_space(3))) void*)l, 16, 0, 0);
}

// Geometry: B=16, C1=128, C2=256, H=W=128, padded spatial 130x130 (1-px zero halo)
#define HP 130
#define XPIX 128              // channels per pixel in x_pad (bf16)
#define YPIX 256              // channels per pixel in y_pad (bf16)
#define XIMG (HP*HP*XPIX)
#define YIMG (HP*HP*YPIX)

// ---------- small prep kernels (fp32 -> bf16 boundary lives here) ----------
__global__ void prep_coef(const float* __restrict__ gamma, const float* __restrict__ beta,
                          const float* __restrict__ mean,  const float* __restrict__ var,
                          const float* __restrict__ b1, float2* __restrict__ coefA, float2* __restrict__ coefB){
  int c = threadIdx.x;
  float s = gamma[c] * rsqrtf(var[c] + 1e-5f);
  float t = beta[c] - mean[c] * s;
  coefA[c] = make_float2(s, t);
  coefB[c] = make_float2(s, b1[c] * s + t);   // fold 1x1 bias into BN shift
}

// w3p[n][k] bf16, k = (kh*3+kw)*128 + c   (matches act K-order (kh,kw,c))
__global__ void repack_w3(const float* __restrict__ w, u16* __restrict__ w3p){
  int idx = blockIdx.x*256 + threadIdx.x;        // n*1152 + k
  int n = idx / 1152, k = idx % 1152;
  int tap = k >> 7, c = k & 127;
  int kh = tap / 3, kw = tap % 3;
  w3p[idx] = f2bf(w[((n*128 + c)*3 + kh)*3 + kw]);
}

// w1p[n][k] bf16 (1x1 conv weight is already [n][c][1][1])
__global__ void repack_w1(const float* __restrict__ w, u16* __restrict__ w1p){
  int idx = blockIdx.x*256 + threadIdx.x;        // 65536 total
  w1p[idx] = f2bf(w[idx]);
}

// zero only the halo rings of x_pad and y_pad chunk buffers
__device__ __forceinline__ void halo_pix(int pi, int& hp, int& wp){
  if (pi < 130){ hp = 0; wp = pi; }
  else if (pi < 260){ hp = 129; wp = pi - 130; }
  else { int j = pi - 260; hp = 1 + (j >> 1); wp = (j & 1) ? 129 : 0; }
}
__global__ void zero_halos(u16* __restrict__ xpad, u16* __restrict__ ypad, int cimg){
  int idx = blockIdx.x*256 + threadIdx.x;
  const int NX = cimg*516*16;
  uint4 z = make_uint4(0u,0u,0u,0u);
  if (idx < NX){
    int b = idx / (516*16), rr = idx % (516*16);
    int pi = rr >> 4, cch = rr & 15, hp, wp;
    halo_pix(pi, hp, wp);
    *(uint4*)(xpad + (((size_t)b*HP + hp)*HP + wp)*XPIX + cch*8) = z;
  } else {
    idx -= NX;
    if (idx < cimg*516*32){
      int b = idx / (516*32), rr = idx % (516*32);
      int pi = rr >> 5, cch = rr & 31, hp, wp;
      halo_pix(pi, hp, wp);
      *(uint4*)(ypad + (((size_t)b*HP + hp)*HP + wp)*YPIX + cch*8) = z;
    }
  }
}

// fp32 NCHW -> padded bf16 NHWC transpose, 64x64 (c x w) tiles via LDS
__global__ __launch_bounds__(256) void transpose_x(const float* __restrict__ x, u16* __restrict__ xpad, int b0){
  __shared__ u16 s[64][66];
  const int tid = threadIdx.x, bid = blockIdx.x;
  const int ct = bid & 1, wt = (bid >> 1) & 1, row = bid >> 2;
  const int bl = row >> 7, h = row & 127;
  const int c0 = ct << 6, w0 = wt << 6;
  {
    const int lw = tid & 63, lc4 = tid >> 6;     // one wave spans one c-row (coalesced fp32)
    const size_t xb = ((size_t)(b0 + bl)*128)*16384 + (size_t)h*128 + w0 + lw;
    #pragma unroll
    for (int r = 0; r < 16; ++r){
      int c = r*4 + lc4;
      s[c][lw] = f2bf(x[xb + (size_t)(c0 + c)*16384]);
    }
  }
  __syncthreads();
  {
    const int lw = tid >> 5, lcp = (tid & 31) << 1;
    const size_t pb = ((size_t)bl*HP + h + 1)*HP;
    #pragma unroll
    for (int r = 0; r < 8; ++r){
      int w = r*8 + lw;
      u32 v = (u32)s[lcp][w] | ((u32)s[lcp+1][w] << 16);
      *(u32*)(xpad + (pb + (w0 + w + 1))*XPIX + c0 + lcp) = v;
    }
  }
}

// ---------- stage A: conv3x3 implicit GEMM + BN + SiLU -> y_pad (NHWC bf16) ----------
__global__ __launch_bounds__(256) void convA(const u16* __restrict__ xpad, const u16* __restrict__ w3p,
                                             const float2* __restrict__ coefA, u16* __restrict__ ypad){
  __shared__ u16 sA[4096];   // act  [p=128][k=32]
  __shared__ u16 sB[4096];   // wts  [n=128][k=32]
  const int tid = threadIdx.x, bid = blockIdx.x;
  const int nt = bid & 1, row = bid >> 1;
  const int bl = row >> 7, h = row & 127;
  const int n0 = nt << 7;
  const int lane = tid & 63, wave = tid >> 6;
  const int wm = wave & 1, wn = wave >> 1;
  const int quad = lane >> 4, l16 = lane & 15;
  const int r0 = tid >> 2, sub = tid & 3;

  f32x4 acc[4][4];
  #pragma unroll
  for (int i = 0; i < 4; ++i)
    #pragma unroll
    for (int j = 0; j < 4; ++j){ f32x4 zz = {0.f,0.f,0.f,0.f}; acc[i][j] = zz; }

  const size_t imgbase = (size_t)bl * XIMG;
  const u16* wrow0 = w3p + (size_t)(n0 + r0)*1152 + sub*8;
  const u16* wrow1 = wrow0 + (size_t)64*1152;

  for (int kt = 0; kt < 36; ++kt){
    const int tap = kt >> 2;
    const int kh = tap / 3, kw = tap % 3;
    const int cc = (kt & 3) << 5;
    const size_t arow = imgbase + (size_t)((h + kh)*HP)*XPIX + cc;
    const u16* ga0 = xpad + arow + (size_t)(r0 + kw)*XPIX + sub*8;
    const u16* ga1 = xpad + arow + (size_t)(r0 + 64 + kw)*XPIX + sub*8;
    __syncthreads();
    gload_lds16(ga0, &sA[tid*8]);
    gload_lds16(ga1, &sA[2048 + tid*8]);
    gload_lds16(wrow0 + kt*32, &sB[tid*8]);
    gload_lds16(wrow1 + kt*32, &sB[2048 + tid*8]);
    __syncthreads();

    bf16x8 af[4], bf[4];
    #pragma unroll
    for (int i = 0; i < 4; ++i) af[i] = *(const bf16x8*)&sA[(wm*64 + i*16 + l16)*32 + quad*8];
    #pragma unroll
    for (int j = 0; j < 4; ++j) bf[j] = *(const bf16x8*)&sB[(wn*64 + j*16 + l16)*32 + quad*8];
    #pragma unroll
    for (int i = 0; i < 4; ++i)
      #pragma unroll
      for (int j = 0; j < 4; ++j)
        acc[i][j] = __builtin_amdgcn_mfma_f32_16x16x32_bf16(af[i], bf[j], acc[i][j], 0, 0, 0);
  }

  // D[pixel = wm*64+i*16+quad*4+r][channel = n0+wn*64+j*16+l16]
  float2 co[4];
  #pragma unroll
  for (int j = 0; j < 4; ++j) co[j] = coefA[n0 + wn*64 + j*16 + l16];
  const size_t ybase = ((size_t)(bl*HP + h + 1))*HP*YPIX;
  #pragma unroll
  for (int i = 0; i < 4; ++i)
    #pragma unroll
    for (int r = 0; r < 4; ++r){
      const int p = wm*64 + i*16 + quad*4 + r;
      const size_t pb = ybase + (size_t)(p + 1)*YPIX + n0 + wn*64;
      #pragma unroll
      for (int j = 0; j < 4; ++j){
        float v = acc[i][j][r] * co[j].x + co[j].y;
        ypad[pb + j*16 + l16] = f2bf(silu(v));
      }
    }
}

// ---------- stage B: shift + conv1x1 + bias + BN + residual + SiLU -> out (NCHW fp32) ----------
__global__ __launch_bounds__(256) void convB(const u16* __restrict__ ypad, const u16* __restrict__ w1p,
                                             const float2* __restrict__ coefB, float* __restrict__ out, int b0){
  __shared__ u16 sAct[4096];  // act [p=128][k=32]
  __shared__ u16 sW[4096];    // wts [n=128][k=32]
  const int tid = threadIdx.x, bid = blockIdx.x;
  const int nt = bid & 1, row = bid >> 1;
  const int bl = row >> 7, h = row & 127;
  const int n0 = nt << 7;
  const int lane = tid & 63, wave = tid >> 6;
  const int wc = wave & 1, wpx = wave >> 1;
  const int quad = lane >> 4, l16 = lane & 15;
  const int r0 = tid >> 2, sub = tid & 3;

  f32x4 acc[4][4];
  #pragma unroll
  for (int i = 0; i < 4; ++i)
    #pragma unroll
    for (int j = 0; j < 4; ++j){ f32x4 zz = {0.f,0.f,0.f,0.f}; acc[i][j] = zz; }

  const size_t imgy = (size_t)bl * YIMG;
  const u16* w_row0 = w1p + (size_t)(n0 + r0)*256 + sub*8;
  const u16* w_row1 = w_row0 + (size_t)64*256;

  // shift taps in padded coords: g0:y[h][w-1] g1:y[h+1][w] g2:y[h][w+1] g3:y[h-1][w]
  #pragma unroll
  for (int kt = 0; kt < 8; ++kt){
    const int g = kt >> 1;
    const int dhp = (g == 0 || g == 2) ? 1 : (g == 1 ? 2 : 0);
    const int dwp = (g == 1 || g == 3) ? 1 : (g == 0 ? 0 : 2);
    const size_t rb = imgy + (size_t)((h + dhp)*HP)*YPIX + kt*32 + sub*8;
    const u16* ga0 = ypad + rb + (size_t)(r0 + dwp)*YPIX;
    const u16* ga1 = ypad + rb + (size_t)(r0 + 64 + dwp)*YPIX;
    __syncthreads();
    gload_lds16(ga0, &sAct[tid*8]);
    gload_lds16(ga1, &sAct[2048 + tid*8]);
    gload_lds16(w_row0 + kt*32, &sW[tid*8]);
    gload_lds16(w_row1 + kt*32, &sW[2048 + tid*8]);
    __syncthreads();

    bf16x8 wf[4], af[4];
    #pragma unroll
    for (int i = 0; i < 4; ++i) wf[i] = *(const bf16x8*)&sW[(wc*64 + i*16 + l16)*32 + quad*8];
    #pragma unroll
    for (int j = 0; j < 4; ++j) af[j] = *(const bf16x8*)&sAct[(wpx*64 + j*16 + l16)*32 + quad*8];
    #pragma unroll
    for (int i = 0; i < 4; ++i)
      #pragma unroll
      for (int j = 0; j < 4; ++j)
        acc[i][j] = __builtin_amdgcn_mfma_f32_16x16x32_bf16(wf[i], af[j], acc[i][j], 0, 0, 0);
  }

  // D[channel = n0+wc*64+i*16+quad*4+r][pixel = wpx*64+j*16+l16]
  const size_t ybase = ((size_t)(bl*HP + h + 1))*HP*YPIX;
  const size_t obase = (size_t)(b0 + bl)*256*16384 + (size_t)h*128;
  #pragma unroll
  for (int i = 0; i < 4; ++i)
    #pragma unroll
    for (int r = 0; r < 4; ++r){
      const int ch = n0 + wc*64 + i*16 + quad*4 + r;
      const float2 co = coefB[ch];
      #pragma unroll
      for (int j = 0; j < 4; ++j){
        const int p = wpx*64 + j*16 + l16;
        float idv = bf2f(ypad[ybase + (size_t)(p + 1)*YPIX + ch]);   // residual (L1-resident)
        float v = acc[i][j][r] * co.x + co.y + idv;
        out[obase + (size_t)ch*16384 + p] = silu(v);
      }
    }
}

// ---------- launch ----------
extern "C" void kernel_launch(void* const* d_in, const int* in_sizes, int n_in,
                              void* d_out, int out_size, void* d_ws, size_t ws_size,
                              hipStream_t stream){
  const float* x  = (const float*)d_in[0];
  const float* w3 = (const float*)d_in[1];
  const float* w1 = (const float*)d_in[2];
  const float* b1 = (const float*)d_in[3];
  const float* gm = (const float*)d_in[4];
  const float* bt = (const float*)d_in[5];
  const float* mn = (const float*)d_in[6];
  const float* vr = (const float*)d_in[7];
  float* outp = (float*)d_out;

  // workspace: small buffers first, then chunk-sized padded image buffers
  char* ws = (char*)d_ws;
  float2* coefA = (float2*)ws;                                // 2048 B
  float2* coefB = coefA + 256;                                // 2048 B
  u16*    w3p   = (u16*)(ws + 4096);                          // 589,824 B
  u16*    w1p   = (u16*)(ws + 4096 + 589824);                 // 131,072 B
  const size_t fixed = 4096 + 589824 + 131072;                // 724,992 B (16B aligned)
  // per-image: xpad 4,326,400 B + ypad 8,652,800 B = 12,979,200 B
  int cimg = 16;
  while (cimg > 1 && fixed + (size_t)cimg*12979200ull > ws_size) cimg >>= 1;
  u16* xpad = (u16*)(ws + fixed);
  u16* ypad = (u16*)(ws + fixed + (size_t)cimg*4326400ull);

  prep_coef<<<1, 256, 0, stream>>>(gm, bt, mn, vr, b1, coefA, coefB);
  repack_w3<<<1152, 256, 0, stream>>>(w3, w3p);
  repack_w1<<<256, 256, 0, stream>>>(w1, w1p);
  {
    int nthr = cimg*516*48;
    zero_halos<<<(nthr + 255)/256, 256, 0, stream>>>(xpad, ypad, cimg);
  }
  for (int b0 = 0; b0 < 16; b0 += cimg){
    transpose_x<<<4*128*cimg, 256, 0, stream>>>(x, xpad, b0);
    convA<<<2*128*cimg, 256, 0, stream>>>(xpad, w3p, coefA, ypad);
    convB<<<2*128*cimg, 256, 0, stream>>>(ypad, w1p, coefB, outp, b0);
  }
}